// Round 9
// baseline (80.335 us; speedup 1.0000x reference)
//
#include <hip/hip_runtime.h>

#define NTOK 16384
#define TB 16

typedef float f32x4_t __attribute__((ext_vector_type(4)));
typedef short s16x8_t __attribute__((ext_vector_type(8)));

union bfpack { unsigned int u[4]; s16x8_t v; };

__device__ __forceinline__ unsigned int pk2bf(float lo, float hi) {
    unsigned int r;
    asm("v_cvt_pk_bf16_f32 %0, %1, %2" : "=v"(r) : "v"(lo), "v"(hi));
    return r;
}
__device__ __forceinline__ unsigned short f2bf(float f) {
    unsigned int r;
    asm("v_cvt_pk_bf16_f32 %0, %1, %1" : "=v"(r) : "v"(f));
    return (unsigned short)r;
}
__device__ __forceinline__ unsigned short f2bf_host_style(float f) {
    unsigned int x = __float_as_uint(f);
    x += 0x7fffu + ((x >> 16) & 1u);
    return (unsigned short)(x >> 16);
}
__device__ __forceinline__ float fexp2(float x) {
#if __has_builtin(__builtin_amdgcn_exp2f)
    return __builtin_amdgcn_exp2f(x);
#else
    return exp2f(x);
#endif
}
__device__ __forceinline__ float frcp(float x) {
#if __has_builtin(__builtin_amdgcn_rcpf)
    return __builtin_amdgcn_rcpf(x);
#else
    return 1.0f / x;
#endif
}
__device__ __forceinline__ float frsq(float x) {
#if __has_builtin(__builtin_amdgcn_rsqf)
    return __builtin_amdgcn_rsqf(x);
#else
    return rsqrtf(x);
#endif
}

// ---- prep: W1T [m][k] (stage0 direct) + attn weights in FRAGMENT order ----
// ushort layout: [0,16384) W1T [m=64][k=256]
//   16384 + mat*4096 (mat = st*5+q): fragment order — ushort offset within matrix
//   = hk*2048 + wv*512 + l*8 + e  holds  W[k = hk*32 + (l>>4)*8 + e][m = wv*16 + (l&15)]
//   so lane l's 16B at (hk,wv) IS its MFMA B-fragment for k-half hk, col-tile wv.
__global__ __launch_bounds__(256)
void prep_kernel(const float* __restrict__ W1,
                 const float* __restrict__ Wq, const float* __restrict__ Wk,
                 const float* __restrict__ Wv, const float* __restrict__ Wf1,
                 const float* __restrict__ Wf2, unsigned short* __restrict__ wsb)
{
    const int i = blockIdx.x * 256 + threadIdx.x;
    if (i < 16384) {
        const int m = i >> 8, k = i & 255;
        wsb[i] = f2bf_host_style(W1[k * 64 + m]);
    } else if (i < 77824) {
        const int u  = i - 16384;
        const int mi = u >> 12;            // matrix 0..14
        const int st = mi / 5, q = mi % 5;
        const int r  = u & 4095;
        const int hk = r >> 11;
        const int r1 = r & 2047;
        const int w  = r1 >> 9;
        const int r2 = r1 & 511;
        const int l  = r2 >> 3;
        const int e  = r2 & 7;
        const int m  = w * 16 + (l & 15);
        const int k  = hk * 32 + (l >> 4) * 8 + e;
        const float* src = q == 0 ? Wq : q == 1 ? Wk : q == 2 ? Wv : q == 3 ? Wf1 : Wf2;
        wsb[i] = f2bf_host_style(src[st * 4096 + k * 64 + m]);
    }
}

__global__ __launch_bounds__(256, 5)
void tf3_kernel(const float* __restrict__ x,
                const float* __restrict__ b1,
                const float* __restrict__ bq, const float* __restrict__ bk,
                const float* __restrict__ bv,
                const float* __restrict__ bf1, const float* __restrict__ bf2,
                const float* __restrict__ lng, const float* __restrict__ lnb,
                const float* __restrict__ Wout, const float* __restrict__ bout,
                const unsigned short* __restrict__ wsb,
                float* __restrict__ out)
{
    // LDS ~14.75 KB. Weight B-fragments live in registers (no LDS staging).
    // x_img (8KB, stage0 only) aliases q_lds∪ky_lds.
    __shared__ __align__(16) char smem[15104];
    unsigned short* a_lds = (unsigned short*)smem;     //  2048 B bf16 A-frags, swizzled
    float* q_lds  = (float*)(smem + 2048);             //  16*68*4
    float* ky_lds = (float*)(smem + 6400);
    float* v_lds  = (float*)(smem + 10752);
    char*  x_img  = smem + 2048;                       //  8 KB alias

    const int tid = threadIdx.x;
    const int wv  = tid >> 6;
    const int l   = tid & 63;
    const int n0  = blockIdx.x * TB;

    const int lr  = l & 15;
    const int q4  = l >> 4;
    const int c   = wv * 16 + lr;

    const int ge = lr;
    const int tg = wv * 4 + q4;

    float res_reg[4], cur_reg[4];

    // direct fragment load: matrix mat, both k-halves -> (r0,r1)
    auto LOADM = [&](int mat, s16x8_t& r0, s16x8_t& r1) {
        const char* gb = (const char*)(wsb + 16384 + mat * 4096) + wv * 1024 + l * 16;
        r0 = *reinterpret_cast<const s16x8_t*>(gb);            // hk=0, 1KB/wave coalesced
        r1 = *reinterpret_cast<const s16x8_t*>(gb + 4096);     // hk=1
    };
    auto mmd = [&](s16x8_t af0, s16x8_t af1, s16x8_t b0, s16x8_t b1) -> f32x4_t {
        f32x4_t acc = __builtin_amdgcn_mfma_f32_16x16x32_bf16(af0, b0, (f32x4_t){0.f,0.f,0.f,0.f}, 0, 0, 0);
        acc = __builtin_amdgcn_mfma_f32_16x16x32_bf16(af1, b1, acc, 0, 0, 0);
        return acc;
    };

    s16x8_t bq0, bq1, bk0, bk1, bv0, bv1;   // QKV fragments
    s16x8_t f10, f11, f20, f21;             // F fragments

    // issue QKV(0) fragment loads (consumed after stage0)
    LOADM(0, bq0, bq1); LOADM(1, bk0, bk1); LOADM(2, bv0, bv1);

    // ---- shared x-convert -> swizzled bf16 image (R8-proven) ----
    {
        const int r  = tid & 15;
        const int cb = tid >> 4;
        const float* xp = x + (size_t)(n0 + r) * 256 + cb * 16;
        const float4 u0 = *reinterpret_cast<const float4*>(xp);
        const float4 u1 = *reinterpret_cast<const float4*>(xp + 4);
        const float4 u2 = *reinterpret_cast<const float4*>(xp + 8);
        const float4 u3 = *reinterpret_cast<const float4*>(xp + 12);
        bfpack P0, P1;
        P0.u[0] = pk2bf(u0.x, u0.y); P0.u[1] = pk2bf(u0.z, u0.w);
        P0.u[2] = pk2bf(u1.x, u1.y); P0.u[3] = pk2bf(u1.z, u1.w);
        P1.u[0] = pk2bf(u2.x, u2.y); P1.u[1] = pk2bf(u2.z, u2.w);
        P1.u[2] = pk2bf(u3.x, u3.y); P1.u[3] = pk2bf(u3.z, u3.w);
        char* rowb = x_img + r * 512;
        *reinterpret_cast<s16x8_t*>(rowb + (((cb * 2    ) ^ (r & 7)) << 4)) = P0.v;
        *reinterpret_cast<s16x8_t*>(rowb + (((cb * 2 + 1) ^ (r & 7)) << 4)) = P1.v;
    }
    __syncthreads();                       // B0a: x-image ready

    // ---- stage 0: h = x @ W1 + b1 (A from x-image, B direct global W1T) ----
    f32x4_t acch = {0.f, 0.f, 0.f, 0.f};
    #pragma unroll
    for (int s5 = 0; s5 < 8; ++s5) {
        const s16x8_t af = *reinterpret_cast<const s16x8_t*>(
            x_img + lr * 512 + (((s5 * 4 + q4) ^ (lr & 7)) << 4));
        const s16x8_t bf = *reinterpret_cast<const s16x8_t*>(&wsb[c * 256 + s5 * 32 + q4 * 8]);
        acch = __builtin_amdgcn_mfma_f32_16x16x32_bf16(af, bf, acch, 0, 0, 0);
    }
    __syncthreads();                       // B0mid: x-image fully consumed (q aliases it)
    {
        const float bb = b1[c];
        #pragma unroll
        for (int rg = 0; rg < 4; ++rg)
            q_lds[(q4 * 4 + rg) * 68 + c] = acch[rg] + bb;
    }
    __syncthreads();                       // B0b: q_lds ready
    #pragma unroll
    for (int tt = 0; tt < 4; ++tt) {       // cur = h, res = leaky(h, 0.1)
        const int t = wv * 4 + tt;
        const float h = q_lds[t * 68 + l];
        cur_reg[tt] = h;
        res_reg[tt] = h >= 0.f ? h : 0.1f * h;
        a_lds[t * 64 + (((l >> 3) ^ (t & 7)) * 8) + (l & 7)] = f2bf(h);
    }

    // ---------------- 3 attention stages ----------------
    for (int st = 0; st < 3; ++st) {
        const float bqv  = bq[st * 64 + c];
        const float bkv  = bk[st * 64 + c];
        const float bvv  = bv[st * 64 + c];
        const float bf1v = bf1[st * 64 + c];
        const float bf2v = bf2[st * 64 + c];
        const float lngv = lng[st * 64 + l];
        const float lnbv = lnb[st * 64 + l];

        __syncthreads();                   // B1: a_lds ready
        {   // QKV: 3 GEMMs, B from registers
            const s16x8_t af0 = *reinterpret_cast<const s16x8_t*>(&a_lds[lr * 64 + ((q4       ^ (lr & 7)) * 8)]);
            const s16x8_t af1 = *reinterpret_cast<const s16x8_t*>(&a_lds[lr * 64 + (((4 + q4) ^ (lr & 7)) * 8)]);
            f32x4_t aq = mmd(af0, af1, bq0, bq1);
            f32x4_t ak = mmd(af0, af1, bk0, bk1);
            f32x4_t av = mmd(af0, af1, bv0, bv1);
            #pragma unroll
            for (int rg = 0; rg < 4; ++rg) {
                const int tr = q4 * 4 + rg;
                q_lds[tr * 68 + c]  = aq[rg] + bqv;
                ky_lds[tr * 68 + c] = ak[rg] + bkv;
                v_lds[tr * 68 + c]  = av[rg] + bvv;
            }
        }
        LOADM(st * 5 + 3, f10, f11);       // F1 frags: latency hidden by attention
        __syncthreads();                   // B2

        // ---- attention core ----
        float kmax_t[4], kmin_t[4];
        {
            const float4 kv = *reinterpret_cast<const float4*>(&ky_lds[tg * 68 + ge * 4]);
            float kmx = fmaxf(fmaxf(kv.x, kv.y), fmaxf(kv.z, kv.w));
            float kmn = fminf(fminf(kv.x, kv.y), fminf(kv.z, kv.w));
            #pragma unroll
            for (int m = 1; m < 16; m <<= 1) {
                kmx = fmaxf(kmx, __shfl_xor(kmx, m, 64));
                kmn = fminf(kmn, __shfl_xor(kmn, m, 64));
            }
            #pragma unroll
            for (int tt = 0; tt < 4; ++tt) {
                kmax_t[tt] = __shfl(kmx, tt * 16, 64);
                kmin_t[tt] = __shfl(kmn, tt * 16, 64);
            }
        }
        #pragma unroll
        for (int tt = 0; tt < 4; ++tt) {
            const int t = wv * 4 + tt;
            const float qs = q_lds[t * 68 + l] * 1.44269504088896340736f;
            const float m2 = fmaxf(qs * kmax_t[tt], qs * kmin_t[tt]);   // exact row max (rank-1)
            const float* kb = &ky_lds[t * 68];
            const float* vb = &v_lds[t * 68];
            float4 ka0 = *reinterpret_cast<const float4*>(kb);
            float4 ka1 = *reinterpret_cast<const float4*>(kb + 4);
            float4 va0 = *reinterpret_cast<const float4*>(vb);
            float4 va1 = *reinterpret_cast<const float4*>(vb + 4);
            float s0 = 0.f, s1 = 0.f, p0 = 0.f, p1 = 0.f;
            #pragma unroll
            for (int j = 0; j < 64; j += 8) {
                float4 kn0, kn1, vn0, vn1;
                if (j < 56) {
                    kn0 = *reinterpret_cast<const float4*>(kb + j + 8);
                    kn1 = *reinterpret_cast<const float4*>(kb + j + 12);
                    vn0 = *reinterpret_cast<const float4*>(vb + j + 8);
                    vn1 = *reinterpret_cast<const float4*>(vb + j + 12);
                }
                const float e0 = fexp2(fmaf(qs, ka0.x, -m2)); s0 += e0; p0 = fmaf(e0, va0.x, p0);
                const float e1 = fexp2(fmaf(qs, ka0.y, -m2)); s1 += e1; p1 = fmaf(e1, va0.y, p1);
                const float e2 = fexp2(fmaf(qs, ka0.z, -m2)); s0 += e2; p0 = fmaf(e2, va0.z, p0);
                const float e3 = fexp2(fmaf(qs, ka0.w, -m2)); s1 += e3; p1 = fmaf(e3, va0.w, p1);
                const float e4 = fexp2(fmaf(qs, ka1.x, -m2)); s0 += e4; p0 = fmaf(e4, va1.x, p0);
                const float e5 = fexp2(fmaf(qs, ka1.y, -m2)); s1 += e5; p1 = fmaf(e5, va1.y, p1);
                const float e6 = fexp2(fmaf(qs, ka1.z, -m2)); s0 += e6; p0 = fmaf(e6, va1.z, p0);
                const float e7 = fexp2(fmaf(qs, ka1.w, -m2)); s1 += e7; p1 = fmaf(e7, va1.w, p1);
                ka0 = kn0; ka1 = kn1; va0 = vn0; va1 = vn1;
            }
            const float y = (p0 + p1) * frcp(s0 + s1) + cur_reg[tt];
            ky_lds[t * 68 + l] = y;
        }
        LOADM(st * 5 + 4, f20, f21);       // F2 frags (L1-hot; short latency)
        __syncthreads();                   // B3

        // ---- F1: h1 = leaky(Y @ Wf1 + bf1, 0.01) -> a_lds bf16 ----
        {
            f32x4_t acc = {0.f, 0.f, 0.f, 0.f};
            #pragma unroll
            for (int kh = 0; kh < 2; ++kh) {
                const float* yp = &ky_lds[lr * 68 + kh * 32 + q4 * 8];
                const float4 y0 = *reinterpret_cast<const float4*>(yp);
                const float4 y1 = *reinterpret_cast<const float4*>(yp + 4);
                bfpack P;
                P.u[0] = pk2bf(y0.x, y0.y); P.u[1] = pk2bf(y0.z, y0.w);
                P.u[2] = pk2bf(y1.x, y1.y); P.u[3] = pk2bf(y1.z, y1.w);
                acc = __builtin_amdgcn_mfma_f32_16x16x32_bf16(P.v, kh ? f11 : f10, acc, 0, 0, 0);
            }
            #pragma unroll
            for (int rg = 0; rg < 4; ++rg) {
                const int tr = q4 * 4 + rg;
                float h = acc[rg] + bf1v;
                h = h >= 0.f ? h : 0.01f * h;
                a_lds[tr * 64 + (((c >> 3) ^ (tr & 7)) * 8) + (c & 7)] = f2bf(h);
            }
        }
        if (st < 2) {                      // next-stage Q,K frags under F2+LN
            LOADM((st + 1) * 5 + 0, bq0, bq1);
            LOADM((st + 1) * 5 + 1, bk0, bk1);
        }
        __syncthreads();                   // B4

        // ---- F2: A = h1 @ Wf2 + bf2 + Y -> ky_lds ----
        {
            const s16x8_t ag0 = *reinterpret_cast<const s16x8_t*>(&a_lds[lr * 64 + ((q4       ^ (lr & 7)) * 8)]);
            const s16x8_t ag1 = *reinterpret_cast<const s16x8_t*>(&a_lds[lr * 64 + (((4 + q4) ^ (lr & 7)) * 8)]);
            f32x4_t acc = mmd(ag0, ag1, f20, f21);
            #pragma unroll
            for (int rg = 0; rg < 4; ++rg) {
                const int tr = q4 * 4 + rg;
                ky_lds[tr * 68 + c] += acc[rg] + bf2v;
            }
        }
        if (st < 2) LOADM((st + 1) * 5 + 2, bv0, bv1);
        __syncthreads();                   // B5

        // ---- LayerNorm + residual; stage cur as bf16 ----
        {
            const float4 av4 = *reinterpret_cast<const float4*>(&ky_lds[tg * 68 + ge * 4]);
            float ssum = av4.x + av4.y + av4.z + av4.w;
            #pragma unroll
            for (int m = 1; m < 16; m <<= 1) ssum += __shfl_xor(ssum, m, 64);
            const float mug = ssum * 0.015625f;
            const float d0 = av4.x - mug, d1 = av4.y - mug, d2 = av4.z - mug, d3 = av4.w - mug;
            float vsum = d0 * d0 + d1 * d1 + d2 * d2 + d3 * d3;
            #pragma unroll
            for (int m = 1; m < 16; m <<= 1) vsum += __shfl_xor(vsum, m, 64);
            #pragma unroll
            for (int tt = 0; tt < 4; ++tt) {
                const int t = wv * 4 + tt;
                const float mu = __shfl(mug, tt * 16, 64);
                const float vv = __shfl(vsum, tt * 16, 64);
                const float rs = frsq(vv * 0.015625f + 1e-5f);
                const float a  = ky_lds[t * 68 + l];
                const float an = (a - mu) * rs * lngv + lnbv;
                const float rnew = res_reg[tt] + an;
                res_reg[tt] = rnew;
                cur_reg[tt] = rnew;
                a_lds[t * 64 + (((l >> 3) ^ (t & 7)) * 8) + (l & 7)] = f2bf(rnew);
            }
        }
    }

    // ---------------- head: leaky(res @ Wout + bout, 0.1), 5 copies ----------------
    const float wo = Wout[l];
    const float bo = bout[0];
    #pragma unroll
    for (int tt = 0; tt < 4; ++tt)
        q_lds[(wv * 4 + tt) * 68 + l] = res_reg[tt] * wo;   // wave-private rows
    {
        const float4 pv = *reinterpret_cast<const float4*>(&q_lds[tg * 68 + ge * 4]);
        float p = pv.x + pv.y + pv.z + pv.w;
        #pragma unroll
        for (int m = 1; m < 16; m <<= 1) p += __shfl_xor(p, m, 64);
        if (ge == 0) {
            float o = p + bo;
            o = o >= 0.f ? o : 0.1f * o;
            #pragma unroll
            for (int c5 = 0; c5 < 5; ++c5)
                out[(size_t)c5 * NTOK + n0 + tg] = o;
        }
    }
}

extern "C" void kernel_launch(void* const* d_in, const int* in_sizes, int n_in,
                              void* d_out, int out_size, void* d_ws, size_t ws_size,
                              hipStream_t stream) {
    const float* x    = (const float*)d_in[0];
    const float* W1   = (const float*)d_in[1];
    const float* b1   = (const float*)d_in[2];
    const float* Wq   = (const float*)d_in[3];
    const float* bq   = (const float*)d_in[4];
    const float* Wk   = (const float*)d_in[5];
    const float* bk   = (const float*)d_in[6];
    const float* Wv   = (const float*)d_in[7];
    const float* bv   = (const float*)d_in[8];
    const float* Wf1  = (const float*)d_in[9];
    const float* bf1  = (const float*)d_in[10];
    const float* Wf2  = (const float*)d_in[11];
    const float* bf2  = (const float*)d_in[12];
    const float* lngp = (const float*)d_in[13];
    const float* lnbp = (const float*)d_in[14];
    const float* Wout = (const float*)d_in[15];
    const float* bout = (const float*)d_in[16];
    float* outp = (float*)d_out;
    unsigned short* wsb = (unsigned short*)d_ws;

    hipLaunchKernelGGL(prep_kernel, dim3(304), dim3(256), 0, stream,
                       W1, Wq, Wk, Wv, Wf1, Wf2, wsb);
    hipLaunchKernelGGL(tf3_kernel, dim3(NTOK / TB), dim3(256), 0, stream,
                       x, b1, bq, bk, bv, bf1, bf2, lngp, lnbp, Wout, bout,
                       (const unsigned short*)wsb, outp);
}

// Round 10
// 54.544 us; speedup vs baseline: 1.4729x; 1.4729x over previous
//
#include <hip/hip_runtime.h>

#define NTOK 16384
#define TB 16

typedef float f32x4_t __attribute__((ext_vector_type(4)));
typedef short s16x8_t __attribute__((ext_vector_type(8)));

union bfpack { unsigned int u[4]; s16x8_t v; };

__device__ __forceinline__ unsigned int pk2bf(float lo, float hi) {
    unsigned int r;
    asm("v_cvt_pk_bf16_f32 %0, %1, %2" : "=v"(r) : "v"(lo), "v"(hi));
    return r;
}
__device__ __forceinline__ unsigned short f2bf(float f) {
    unsigned int r;
    asm("v_cvt_pk_bf16_f32 %0, %1, %1" : "=v"(r) : "v"(f));
    return (unsigned short)r;
}
__device__ __forceinline__ unsigned short f2bf_host_style(float f) {
    unsigned int x = __float_as_uint(f);
    x += 0x7fffu + ((x >> 16) & 1u);
    return (unsigned short)(x >> 16);
}
__device__ __forceinline__ float fexp2(float x) {
#if __has_builtin(__builtin_amdgcn_exp2f)
    return __builtin_amdgcn_exp2f(x);
#else
    return exp2f(x);
#endif
}
__device__ __forceinline__ float frcp(float x) {
#if __has_builtin(__builtin_amdgcn_rcpf)
    return __builtin_amdgcn_rcpf(x);
#else
    return 1.0f / x;
#endif
}
__device__ __forceinline__ float frsq(float x) {
#if __has_builtin(__builtin_amdgcn_rsqf)
    return __builtin_amdgcn_rsqf(x);
#else
    return rsqrtf(x);
#endif
}

// ---- prep: W1T [m][k] (stage0 direct) + attn weights in FRAGMENT order ----
// ushort layout: [0,16384) W1T [m=64][k=256]
//   16384 + mat*4096 (mat = st*5+q): fragment order — ushort offset within matrix
//   = hk*2048 + wv*512 + l*8 + e  holds  W[k = hk*32 + (l>>4)*8 + e][m = wv*16 + (l&15)]
//   so lane l's 16B at (hk,wv) IS its MFMA B-fragment for k-half hk, col-tile wv.
__global__ __launch_bounds__(256)
void prep_kernel(const float* __restrict__ W1,
                 const float* __restrict__ Wq, const float* __restrict__ Wk,
                 const float* __restrict__ Wv, const float* __restrict__ Wf1,
                 const float* __restrict__ Wf2, unsigned short* __restrict__ wsb)
{
    const int i = blockIdx.x * 256 + threadIdx.x;
    if (i < 16384) {
        const int m = i >> 8, k = i & 255;
        wsb[i] = f2bf_host_style(W1[k * 64 + m]);
    } else if (i < 77824) {
        const int u  = i - 16384;
        const int mi = u >> 12;            // matrix 0..14
        const int st = mi / 5, q = mi % 5;
        const int r  = u & 4095;
        const int hk = r >> 11;
        const int r1 = r & 2047;
        const int w  = r1 >> 9;
        const int r2 = r1 & 511;
        const int l  = r2 >> 3;
        const int e  = r2 & 7;
        const int m  = w * 16 + (l & 15);
        const int k  = hk * 32 + (l >> 4) * 8 + e;
        const float* src = q == 0 ? Wq : q == 1 ? Wk : q == 2 ? Wv : q == 3 ? Wf1 : Wf2;
        wsb[i] = f2bf_host_style(src[st * 4096 + k * 64 + m]);
    }
}

__global__ __launch_bounds__(256, 4)
void tf3_kernel(const float* __restrict__ x,
                const float* __restrict__ b1,
                const float* __restrict__ bq, const float* __restrict__ bk,
                const float* __restrict__ bv,
                const float* __restrict__ bf1, const float* __restrict__ bf2,
                const float* __restrict__ lng, const float* __restrict__ lnb,
                const float* __restrict__ Wout, const float* __restrict__ bout,
                const unsigned short* __restrict__ wsb,
                float* __restrict__ out)
{
    // LDS ~14.75 KB. Weight B-fragments live in registers (no LDS staging).
    // x_img (8KB, stage0 only) aliases q_lds∪ky_lds.
    __shared__ __align__(16) char smem[15104];
    unsigned short* a_lds = (unsigned short*)smem;     //  2048 B bf16 A-frags, swizzled
    float* q_lds  = (float*)(smem + 2048);             //  16*68*4
    float* ky_lds = (float*)(smem + 6400);
    float* v_lds  = (float*)(smem + 10752);
    char*  x_img  = smem + 2048;                       //  8 KB alias

    const int tid = threadIdx.x;
    const int wv  = tid >> 6;
    const int l   = tid & 63;
    const int n0  = blockIdx.x * TB;

    const int lr  = l & 15;
    const int q4  = l >> 4;
    const int c   = wv * 16 + lr;

    const int ge = lr;
    const int tg = wv * 4 + q4;

    float res_reg[4], cur_reg[4];

    // direct fragment load: matrix mat, both k-halves -> (r0,r1)
    auto LOADM = [&](int mat, s16x8_t& r0, s16x8_t& r1) {
        const char* gb = (const char*)(wsb + 16384 + mat * 4096) + wv * 1024 + l * 16;
        r0 = *reinterpret_cast<const s16x8_t*>(gb);            // hk=0, 1KB/wave coalesced
        r1 = *reinterpret_cast<const s16x8_t*>(gb + 4096);     // hk=1
    };
    auto mmd = [&](s16x8_t af0, s16x8_t af1, s16x8_t b0, s16x8_t b1) -> f32x4_t {
        f32x4_t acc = __builtin_amdgcn_mfma_f32_16x16x32_bf16(af0, b0, (f32x4_t){0.f,0.f,0.f,0.f}, 0, 0, 0);
        acc = __builtin_amdgcn_mfma_f32_16x16x32_bf16(af1, b1, acc, 0, 0, 0);
        return acc;
    };

    s16x8_t bq0, bq1, bk0, bk1, bv0, bv1;   // QKV fragments
    s16x8_t f10, f11, f20, f21;             // F fragments

    // issue QKV(0) fragment loads (consumed after stage0)
    LOADM(0, bq0, bq1); LOADM(1, bk0, bk1); LOADM(2, bv0, bv1);

    // ---- shared x-convert -> swizzled bf16 image ----
    {
        const int r  = tid & 15;
        const int cb = tid >> 4;
        const float* xp = x + (size_t)(n0 + r) * 256 + cb * 16;
        const float4 u0 = *reinterpret_cast<const float4*>(xp);
        const float4 u1 = *reinterpret_cast<const float4*>(xp + 4);
        const float4 u2 = *reinterpret_cast<const float4*>(xp + 8);
        const float4 u3 = *reinterpret_cast<const float4*>(xp + 12);
        bfpack P0, P1;
        P0.u[0] = pk2bf(u0.x, u0.y); P0.u[1] = pk2bf(u0.z, u0.w);
        P0.u[2] = pk2bf(u1.x, u1.y); P0.u[3] = pk2bf(u1.z, u1.w);
        P1.u[0] = pk2bf(u2.x, u2.y); P1.u[1] = pk2bf(u2.z, u2.w);
        P1.u[2] = pk2bf(u3.x, u3.y); P1.u[3] = pk2bf(u3.z, u3.w);
        char* rowb = x_img + r * 512;
        *reinterpret_cast<s16x8_t*>(rowb + (((cb * 2    ) ^ (r & 7)) << 4)) = P0.v;
        *reinterpret_cast<s16x8_t*>(rowb + (((cb * 2 + 1) ^ (r & 7)) << 4)) = P1.v;
    }
    __syncthreads();                       // B0a: x-image ready

    // ---- stage 0: h = x @ W1 + b1 (A from x-image, B direct global W1T) ----
    f32x4_t acch = {0.f, 0.f, 0.f, 0.f};
    #pragma unroll
    for (int s5 = 0; s5 < 8; ++s5) {
        const s16x8_t af = *reinterpret_cast<const s16x8_t*>(
            x_img + lr * 512 + (((s5 * 4 + q4) ^ (lr & 7)) << 4));
        const s16x8_t bf = *reinterpret_cast<const s16x8_t*>(&wsb[c * 256 + s5 * 32 + q4 * 8]);
        acch = __builtin_amdgcn_mfma_f32_16x16x32_bf16(af, bf, acch, 0, 0, 0);
    }
    __syncthreads();                       // B0mid: x-image fully consumed (q aliases it)
    {
        const float bb = b1[c];
        #pragma unroll
        for (int rg = 0; rg < 4; ++rg)
            q_lds[(q4 * 4 + rg) * 68 + c] = acch[rg] + bb;
    }
    __syncthreads();                       // B0b: q_lds ready
    #pragma unroll
    for (int tt = 0; tt < 4; ++tt) {       // cur = h, res = leaky(h, 0.1)
        const int t = wv * 4 + tt;
        const float h = q_lds[t * 68 + l];
        cur_reg[tt] = h;
        res_reg[tt] = h >= 0.f ? h : 0.1f * h;
        a_lds[t * 64 + (((l >> 3) ^ (t & 7)) * 8) + (l & 7)] = f2bf(h);
    }

    // ---------------- 3 attention stages ----------------
    for (int st = 0; st < 3; ++st) {
        const float bqv  = bq[st * 64 + c];
        const float bkv  = bk[st * 64 + c];
        const float bvv  = bv[st * 64 + c];
        const float bf1v = bf1[st * 64 + c];
        const float bf2v = bf2[st * 64 + c];
        const float lngv = lng[st * 64 + l];
        const float lnbv = lnb[st * 64 + l];

        __syncthreads();                   // B1: a_lds ready
        {   // QKV: 3 GEMMs, B from registers
            const s16x8_t af0 = *reinterpret_cast<const s16x8_t*>(&a_lds[lr * 64 + ((q4       ^ (lr & 7)) * 8)]);
            const s16x8_t af1 = *reinterpret_cast<const s16x8_t*>(&a_lds[lr * 64 + (((4 + q4) ^ (lr & 7)) * 8)]);
            f32x4_t aq = mmd(af0, af1, bq0, bq1);
            f32x4_t ak = mmd(af0, af1, bk0, bk1);
            f32x4_t av = mmd(af0, af1, bv0, bv1);
            #pragma unroll
            for (int rg = 0; rg < 4; ++rg) {
                const int tr = q4 * 4 + rg;
                q_lds[tr * 68 + c]  = aq[rg] + bqv;
                ky_lds[tr * 68 + c] = ak[rg] + bkv;
                v_lds[tr * 68 + c]  = av[rg] + bvv;
            }
        }
        LOADM(st * 5 + 3, f10, f11);       // F1 frags: latency hidden by attention
        __syncthreads();                   // B2

        // ---- attention core ----
        float kmax_t[4], kmin_t[4];
        {
            const float4 kv = *reinterpret_cast<const float4*>(&ky_lds[tg * 68 + ge * 4]);
            float kmx = fmaxf(fmaxf(kv.x, kv.y), fmaxf(kv.z, kv.w));
            float kmn = fminf(fminf(kv.x, kv.y), fminf(kv.z, kv.w));
            #pragma unroll
            for (int m = 1; m < 16; m <<= 1) {
                kmx = fmaxf(kmx, __shfl_xor(kmx, m, 64));
                kmn = fminf(kmn, __shfl_xor(kmn, m, 64));
            }
            #pragma unroll
            for (int tt = 0; tt < 4; ++tt) {
                kmax_t[tt] = __shfl(kmx, tt * 16, 64);
                kmin_t[tt] = __shfl(kmn, tt * 16, 64);
            }
        }
        #pragma unroll
        for (int tt = 0; tt < 4; ++tt) {
            const int t = wv * 4 + tt;
            const float qs = q_lds[t * 68 + l] * 1.44269504088896340736f;
            const float m2 = fmaxf(qs * kmax_t[tt], qs * kmin_t[tt]);   // exact row max (rank-1)
            const float* kb = &ky_lds[t * 68];
            const float* vb = &v_lds[t * 68];
            float4 ka0 = *reinterpret_cast<const float4*>(kb);
            float4 ka1 = *reinterpret_cast<const float4*>(kb + 4);
            float4 va0 = *reinterpret_cast<const float4*>(vb);
            float4 va1 = *reinterpret_cast<const float4*>(vb + 4);
            float s0 = 0.f, s1 = 0.f, p0 = 0.f, p1 = 0.f;
            #pragma unroll
            for (int j = 0; j < 64; j += 8) {
                float4 kn0, kn1, vn0, vn1;
                if (j < 56) {
                    kn0 = *reinterpret_cast<const float4*>(kb + j + 8);
                    kn1 = *reinterpret_cast<const float4*>(kb + j + 12);
                    vn0 = *reinterpret_cast<const float4*>(vb + j + 8);
                    vn1 = *reinterpret_cast<const float4*>(vb + j + 12);
                }
                const float e0 = fexp2(fmaf(qs, ka0.x, -m2)); s0 += e0; p0 = fmaf(e0, va0.x, p0);
                const float e1 = fexp2(fmaf(qs, ka0.y, -m2)); s1 += e1; p1 = fmaf(e1, va0.y, p1);
                const float e2 = fexp2(fmaf(qs, ka0.z, -m2)); s0 += e2; p0 = fmaf(e2, va0.z, p0);
                const float e3 = fexp2(fmaf(qs, ka0.w, -m2)); s1 += e3; p1 = fmaf(e3, va0.w, p1);
                const float e4 = fexp2(fmaf(qs, ka1.x, -m2)); s0 += e4; p0 = fmaf(e4, va1.x, p0);
                const float e5 = fexp2(fmaf(qs, ka1.y, -m2)); s1 += e5; p1 = fmaf(e5, va1.y, p1);
                const float e6 = fexp2(fmaf(qs, ka1.z, -m2)); s0 += e6; p0 = fmaf(e6, va1.z, p0);
                const float e7 = fexp2(fmaf(qs, ka1.w, -m2)); s1 += e7; p1 = fmaf(e7, va1.w, p1);
                ka0 = kn0; ka1 = kn1; va0 = vn0; va1 = vn1;
            }
            const float y = (p0 + p1) * frcp(s0 + s1) + cur_reg[tt];
            ky_lds[t * 68 + l] = y;
        }
        LOADM(st * 5 + 4, f20, f21);       // F2 frags (L1/L2-hot; short latency)
        __syncthreads();                   // B3

        // ---- F1: h1 = leaky(Y @ Wf1 + bf1, 0.01) -> a_lds bf16 ----
        {
            f32x4_t acc = {0.f, 0.f, 0.f, 0.f};
            #pragma unroll
            for (int kh = 0; kh < 2; ++kh) {
                const float* yp = &ky_lds[lr * 68 + kh * 32 + q4 * 8];
                const float4 y0 = *reinterpret_cast<const float4*>(yp);
                const float4 y1 = *reinterpret_cast<const float4*>(yp + 4);
                bfpack P;
                P.u[0] = pk2bf(y0.x, y0.y); P.u[1] = pk2bf(y0.z, y0.w);
                P.u[2] = pk2bf(y1.x, y1.y); P.u[3] = pk2bf(y1.z, y1.w);
                acc = __builtin_amdgcn_mfma_f32_16x16x32_bf16(P.v, kh ? f11 : f10, acc, 0, 0, 0);
            }
            #pragma unroll
            for (int rg = 0; rg < 4; ++rg) {
                const int tr = q4 * 4 + rg;
                float h = acc[rg] + bf1v;
                h = h >= 0.f ? h : 0.01f * h;
                a_lds[tr * 64 + (((c >> 3) ^ (tr & 7)) * 8) + (c & 7)] = f2bf(h);
            }
        }
        if (st < 2) {                      // next-stage Q,K frags under F2+LN
            LOADM((st + 1) * 5 + 0, bq0, bq1);
            LOADM((st + 1) * 5 + 1, bk0, bk1);
        }
        __syncthreads();                   // B4

        // ---- F2: A = h1 @ Wf2 + bf2 + Y -> ky_lds ----
        {
            const s16x8_t ag0 = *reinterpret_cast<const s16x8_t*>(&a_lds[lr * 64 + ((q4       ^ (lr & 7)) * 8)]);
            const s16x8_t ag1 = *reinterpret_cast<const s16x8_t*>(&a_lds[lr * 64 + (((4 + q4) ^ (lr & 7)) * 8)]);
            f32x4_t acc = mmd(ag0, ag1, f20, f21);
            #pragma unroll
            for (int rg = 0; rg < 4; ++rg) {
                const int tr = q4 * 4 + rg;
                ky_lds[tr * 68 + c] += acc[rg] + bf2v;
            }
        }
        if (st < 2) LOADM((st + 1) * 5 + 2, bv0, bv1);
        __syncthreads();                   // B5

        // ---- LayerNorm + residual; stage cur as bf16 ----
        {
            const float4 av4 = *reinterpret_cast<const float4*>(&ky_lds[tg * 68 + ge * 4]);
            float ssum = av4.x + av4.y + av4.z + av4.w;
            #pragma unroll
            for (int m = 1; m < 16; m <<= 1) ssum += __shfl_xor(ssum, m, 64);
            const float mug = ssum * 0.015625f;
            const float d0 = av4.x - mug, d1 = av4.y - mug, d2 = av4.z - mug, d3 = av4.w - mug;
            float vsum = d0 * d0 + d1 * d1 + d2 * d2 + d3 * d3;
            #pragma unroll
            for (int m = 1; m < 16; m <<= 1) vsum += __shfl_xor(vsum, m, 64);
            #pragma unroll
            for (int tt = 0; tt < 4; ++tt) {
                const int t = wv * 4 + tt;
                const float mu = __shfl(mug, tt * 16, 64);
                const float vv = __shfl(vsum, tt * 16, 64);
                const float rs = frsq(vv * 0.015625f + 1e-5f);
                const float a  = ky_lds[t * 68 + l];
                const float an = (a - mu) * rs * lngv + lnbv;
                const float rnew = res_reg[tt] + an;
                res_reg[tt] = rnew;
                cur_reg[tt] = rnew;
                a_lds[t * 64 + (((l >> 3) ^ (t & 7)) * 8) + (l & 7)] = f2bf(rnew);
            }
        }
    }

    // ---------------- head: leaky(res @ Wout + bout, 0.1), 5 copies ----------------
    const float wo = Wout[l];
    const float bo = bout[0];
    #pragma unroll
    for (int tt = 0; tt < 4; ++tt)
        q_lds[(wv * 4 + tt) * 68 + l] = res_reg[tt] * wo;   // wave-private rows
    {
        const float4 pv = *reinterpret_cast<const float4*>(&q_lds[tg * 68 + ge * 4]);
        float p = pv.x + pv.y + pv.z + pv.w;
        #pragma unroll
        for (int m = 1; m < 16; m <<= 1) p += __shfl_xor(p, m, 64);
        if (ge == 0) {
            float o = p + bo;
            o = o >= 0.f ? o : 0.1f * o;
            #pragma unroll
            for (int c5 = 0; c5 < 5; ++c5)
                out[(size_t)c5 * NTOK + n0 + tg] = o;
        }
    }
}

extern "C" void kernel_launch(void* const* d_in, const int* in_sizes, int n_in,
                              void* d_out, int out_size, void* d_ws, size_t ws_size,
                              hipStream_t stream) {
    const float* x    = (const float*)d_in[0];
    const float* W1   = (const float*)d_in[1];
    const float* b1   = (const float*)d_in[2];
    const float* Wq   = (const float*)d_in[3];
    const float* bq   = (const float*)d_in[4];
    const float* Wk   = (const float*)d_in[5];
    const float* bk   = (const float*)d_in[6];
    const float* Wv   = (const float*)d_in[7];
    const float* bv   = (const float*)d_in[8];
    const float* Wf1  = (const float*)d_in[9];
    const float* bf1  = (const float*)d_in[10];
    const float* Wf2  = (const float*)d_in[11];
    const float* bf2  = (const float*)d_in[12];
    const float* lngp = (const float*)d_in[13];
    const float* lnbp = (const float*)d_in[14];
    const float* Wout = (const float*)d_in[15];
    const float* bout = (const float*)d_in[16];
    float* outp = (float*)d_out;
    unsigned short* wsb = (unsigned short*)d_ws;

    hipLaunchKernelGGL(prep_kernel, dim3(304), dim3(256), 0, stream,
                       W1, Wq, Wk, Wv, Wf1, Wf2, wsb);
    hipLaunchKernelGGL(tf3_kernel, dim3(NTOK / TB), dim3(256), 0, stream,
                       x, b1, bq, bk, bv, bf1, bf2, lngp, lnbp, Wout, bout,
                       (const unsigned short*)wsb, outp);
}